// Round 8
// baseline (2210.799 us; speedup 1.0000x reference)
//
#include <hip/hip_runtime.h>
#include <hip/hip_bf16.h>

typedef unsigned short u16;

#define NN    100000     // total nodes
#define NU    50000      // users
#define DD    64         // latdim
#define HHY   128        // hyperNum
#define EE    1600000    // nnz
#define NCHK  64         // split-K chunks for lat
#define CROWS 1563       // ceil(NN/NCHK)

__device__ __forceinline__ float us2f(u16 u) {
    union { unsigned int i; float f; } v; v.i = ((unsigned int)u) << 16; return v.f;
}
__device__ __forceinline__ u16 f2us(float f) {
    __hip_bfloat16 b = __float2bfloat16(f);
    return *reinterpret_cast<u16*>(&b);
}
__device__ __forceinline__ float lrelu(float x) { return x > 0.f ? x : 0.5f * x; }

// ---------------- CSR build: histogram -> scan -> scatter ----------------

__global__ __launch_bounds__(256) void k_hist(const int* __restrict__ rows, int* __restrict__ cnt) {
    int e = blockIdx.x * 256 + threadIdx.x;
    if (e < EE) atomicAdd(&cnt[rows[e]], 1);
}

__global__ __launch_bounds__(1024) void k_scan(const int* __restrict__ cnt,
                                               int* __restrict__ row_start,
                                               int* __restrict__ cursor) {
    __shared__ int sums[1024];
    const int t = threadIdx.x;
    const int CPT = (NN + 1023) / 1024;   // 98
    const int base = t * CPT;
    int s = 0;
    for (int i = 0; i < CPT; i++) { int idx = base + i; if (idx < NN) s += cnt[idx]; }
    sums[t] = s;
    __syncthreads();
    for (int off = 1; off < 1024; off <<= 1) {
        int add = (t >= off) ? sums[t - off] : 0;
        __syncthreads();
        sums[t] += add;
        __syncthreads();
    }
    int run = sums[t] - s;   // exclusive prefix of this thread's chunk
    for (int i = 0; i < CPT; i++) {
        int idx = base + i;
        if (idx < NN) { int c = cnt[idx]; row_start[idx] = run; cursor[idx] = run; run += c; }
    }
    if (t == 1023) row_start[NN] = sums[1023];
}

__global__ __launch_bounds__(256) void k_scatter(const int* __restrict__ rows,
                                                 const int* __restrict__ cols,
                                                 const float* __restrict__ vals,
                                                 int* __restrict__ cursor,
                                                 int2* __restrict__ csr) {
    int e = blockIdx.x * 256 + threadIdx.x;
    if (e >= EE) return;
    int r = rows[e];
    int pos = atomicAdd(&cursor[r], 1);
    csr[pos] = make_int2(cols[e], __float_as_int(vals[e]));
}

// ---------------- embeds0 = concat(u,i) -> cur (bf16), fp32 inputs ----------------

__global__ __launch_bounds__(256) void k_prep(const float4* __restrict__ u,
                                              const float4* __restrict__ it,
                                              ushort4* __restrict__ cur) {
    int idx = blockIdx.x * 256 + threadIdx.x;
    const int HALF = NU * DD / 4;  // 800000
    if (idx >= 2 * HALF) return;
    float4 f = (idx < HALF) ? u[idx] : it[idx - HALF];
    ushort4 o; o.x = f2us(f.x); o.y = f2us(f.y); o.z = f2us(f.z); o.w = f2us(f.w);
    cur[idx] = o;
}

// ---------------- allHyper = embeds0 @ Hyper  [NN x HHY], Hyper fp32 [D,H] ----------------

__global__ __launch_bounds__(256) void k_allhyper(const u16* __restrict__ cur,
                                                  const float* __restrict__ Hyper,
                                                  u16* __restrict__ hyp) {
    int t = threadIdx.x;
    int hg = t & 31;                      // 32 groups of 4 h
    int n = blockIdx.x * 8 + (t >> 5);
    const ushort4* e4 = (const ushort4*)(cur + (size_t)n * DD);
    ushort4 er[16];
#pragma unroll
    for (int i = 0; i < 16; i++) er[i] = e4[i];
    float a0 = 0.f, a1 = 0.f, a2 = 0.f, a3 = 0.f;
#pragma unroll
    for (int i = 0; i < 16; i++) {
        u16 ev[4] = { er[i].x, er[i].y, er[i].z, er[i].w };
#pragma unroll
        for (int k = 0; k < 4; k++) {
            int d = i * 4 + k;
            float e = us2f(ev[k]);
            float4 hq = *(const float4*)(Hyper + (size_t)d * HHY + hg * 4);
            a0 += e * hq.x; a1 += e * hq.y;
            a2 += e * hq.z; a3 += e * hq.w;
        }
    }
    u16* o = hyp + (size_t)n * HHY + hg * 4;
    o[0] = f2us(a0); o[1] = f2us(a1); o[2] = f2us(a2); o[3] = f2us(a3);
}

// ---------------- gate = cur * (2*sigmoid(z)-1), z fp32 ----------------

__global__ __launch_bounds__(256) void k_gate(const ushort4* __restrict__ cur,
                                              const float4* __restrict__ z,
                                              ushort4* __restrict__ gate) {
    int idx = blockIdx.x * 256 + threadIdx.x;
    if (idx >= NN * DD / 4) return;
    ushort4 c = cur[idx];
    float4 zz = z[idx];
    ushort4 o;
    o.x = f2us(us2f(c.x) * (2.f / (1.f + __expf(-zz.x)) - 1.f));
    o.y = f2us(us2f(c.y) * (2.f / (1.f + __expf(-zz.y)) - 1.f));
    o.z = f2us(us2f(c.z) * (2.f / (1.f + __expf(-zz.z)) - 1.f));
    o.w = f2us(us2f(c.w) * (2.f / (1.f + __expf(-zz.w)) - 1.f));
    gate[idx] = o;
}

// ---------------- SpMM: tem = leaky(A @ gate), one wave per row; fp32 out ----------------

__global__ __launch_bounds__(256) void k_spmm(const int* __restrict__ row_start,
                                              const int2* __restrict__ csr,
                                              const u16* __restrict__ gate,
                                              float* __restrict__ out0) {
    int w = threadIdx.x >> 6, d = threadIdx.x & 63;
    int row = blockIdx.x * 4 + w;
    if (row >= NN) return;
    int s = row_start[row], e = row_start[row + 1];
    float acc = 0.f;
    for (int j = s; j < e; j++) {
        int2 cv = csr[j];
        acc += __int_as_float(cv.y) * us2f(gate[(size_t)cv.x * DD + d]);
    }
    out0[(size_t)row * DD + d] = lrelu(acc);
}

// ---------------- lat partials: part[chunk][h][d] = sum_n hyp[n,h]*cur[n,d] ----

__global__ __launch_bounds__(256) void k_latpart(const u16* __restrict__ cur,
                                                 const u16* __restrict__ hyp,
                                                 float* __restrict__ part) {
    int w = threadIdx.x >> 6, d = threadIdx.x & 63;
    int h0 = (blockIdx.y * 4 + w) * 16;
    int chunk = blockIdx.x;
    int c0 = chunk * CROWS;
    int c1 = c0 + CROWS; if (c1 > NN) c1 = NN;
    float acc[16];
#pragma unroll
    for (int j = 0; j < 16; j++) acc[j] = 0.f;
    for (int n = c0; n < c1; n++) {
        float cv = us2f(cur[(size_t)n * DD + d]);
        const ushort4* hp = (const ushort4*)(hyp + (size_t)n * HHY + h0);
        u16 ha[16];
        *(ushort4*)(ha + 0)  = hp[0];
        *(ushort4*)(ha + 4)  = hp[1];
        *(ushort4*)(ha + 8)  = hp[2];
        *(ushort4*)(ha + 12) = hp[3];
#pragma unroll
        for (int j = 0; j < 16; j++) acc[j] += us2f(ha[j]) * cv;
    }
#pragma unroll
    for (int j = 0; j < 16; j++)
        part[((size_t)chunk * HHY + h0 + j) * DD + d] = acc[j];
}

__global__ __launch_bounds__(256) void k_latreduce(const float* __restrict__ part,
                                                   float* __restrict__ lat) {
    int idx = blockIdx.x * 256 + threadIdx.x;   // h*64+d, 8192 total
    float s = 0.f;
    for (int c = 0; c < NCHK; c++) s += part[(size_t)c * HHY * DD + idx];
    lat[idx] = lrelu(s);
}

// ---- hyperLat = leaky(hyp @ lat); outL (fp32) = hyperLat; cur (bf16) = hyperLat + tem ----

__global__ __launch_bounds__(256) void k_hyperlat(const u16* __restrict__ hyp,
                                                  const float* __restrict__ lat,
                                                  const float* __restrict__ tem0,
                                                  float* __restrict__ outL,
                                                  u16* __restrict__ cur) {
    __shared__ float lds[HHY * DD];   // 32 KB
    int t = threadIdx.x;
    for (int i = t; i < HHY * DD; i += 256) lds[i] = lat[i];
    __syncthreads();
    int w = t >> 6, d = t & 63;
    int r0 = blockIdx.x * 16 + w * 4;
    float acc[4] = {0.f, 0.f, 0.f, 0.f};
    for (int h0 = 0; h0 < HHY; h0 += 8) {
        u16 hr[4][8];
#pragma unroll
        for (int r = 0; r < 4; r++) {
            const ushort4* p = (const ushort4*)(hyp + (size_t)(r0 + r) * HHY + h0);
            ushort4 a = p[0], b = p[1];
            hr[r][0] = a.x; hr[r][1] = a.y; hr[r][2] = a.z; hr[r][3] = a.w;
            hr[r][4] = b.x; hr[r][5] = b.y; hr[r][6] = b.z; hr[r][7] = b.w;
        }
#pragma unroll
        for (int j = 0; j < 8; j++) {
            float lv = lds[(h0 + j) * DD + d];
#pragma unroll
            for (int r = 0; r < 4; r++) acc[r] += us2f(hr[r][j]) * lv;
        }
    }
#pragma unroll
    for (int r = 0; r < 4; r++) {
        size_t off = (size_t)(r0 + r) * DD + d;
        float hl = lrelu(acc[r]);
        float tem = tem0[off];
        outL[off] = hl;                 // fp32 output
        cur[off] = f2us(hl + tem);      // bf16 intermediate for next layer
    }
}

// ---------------- launch ----------------

extern "C" void kernel_launch(void* const* d_in, const int* in_sizes, int n_in,
                              void* d_out, int out_size, void* d_ws, size_t ws_size,
                              hipStream_t stream) {
    const int*   rows  = (const int*)d_in[0];    // int32
    const int*   cols  = (const int*)d_in[1];    // int32
    const float* vals  = (const float*)d_in[2];  // fp32
    const float* uEmb  = (const float*)d_in[3];  // fp32
    const float* iEmb  = (const float*)d_in[4];  // fp32
    const float* Hyper = (const float*)d_in[5];  // fp32
    const float* zishi = (const float*)d_in[6];  // fp32
    // d_in[7] = keepRate (==1, static python branch) -> unused

    float* out = (float*)d_out;                  // fp32 output, [3, NN, DD]

    char* ws = (char*)d_ws;
    // workspace layout identical to R4's proven range (< 54.6 MB)
    int2*  csr       = (int2*)(ws + 0);                 // 12,800,000
    int*   row_start = (int*)(ws + 12800000);           //    400,128 (padded)
    int*   cursor    = (int*)(ws + 13200128);           //    400,000
    int*   counts    = (int*)(ws + 13600128);           //    400,000
    u16*   hyp       = (u16*)(ws + 14000128);           // 25,600,000
    u16*   cur       = (u16*)(ws + 39600128);           // 12,800,000
    float* part      = (float*)(ws + 52400128);         //  2,097,152
    float* lat       = (float*)(ws + 54497280);         //     32,768 -> end 54,530,048

    // gate (bf16, 12.8 MB) aliases the first half of d_out's fp32 hyperLat2 slab
    // (bytes 51.2MB..64MB); consumed by k_spmm before k_hyperlat(l2) overwrites it.
    u16* gate = (u16*)(out + (size_t)2 * NN * DD);

    // CSR build
    hipMemsetAsync(counts, 0, NN * sizeof(int), stream);
    k_hist<<<(EE + 255) / 256, 256, 0, stream>>>(rows, counts);
    k_scan<<<1, 1024, 0, stream>>>(counts, row_start, cursor);
    k_scatter<<<(EE + 255) / 256, 256, 0, stream>>>(rows, cols, vals, cursor, csr);

    // embeds0 + allHyper
    k_prep<<<(NN * DD / 4 + 255) / 256, 256, 0, stream>>>((const float4*)uEmb, (const float4*)iEmb, (ushort4*)cur);
    k_allhyper<<<NN / 8, 256, 0, stream>>>(cur, Hyper, hyp);

    float* out0 = out;  // tem slab (layer-2 spmm overwrites it, matching reference)
    for (int l = 0; l < 2; l++) {
        k_gate<<<(NN * DD / 4 + 255) / 256, 256, 0, stream>>>((const ushort4*)cur, (const float4*)zishi, (ushort4*)gate);
        k_spmm<<<NN / 4, 256, 0, stream>>>(row_start, csr, gate, out0);
        k_latpart<<<dim3(NCHK, 2), 256, 0, stream>>>(cur, hyp, part);
        k_latreduce<<<HHY * DD / 256, 256, 0, stream>>>(part, lat);
        k_hyperlat<<<NN / 16, 256, 0, stream>>>(hyp, lat, out0, out + (size_t)(1 + l) * NN * DD, cur);
    }
}